// Round 7
// baseline (32485.089 us; speedup 1.0000x reference)
//
#include <hip/hip_runtime.h>
#include <stdint.h>

#define T_STEPS 8192
#define K_TAGS 1024
#define D_DIM 1024
#define START_TAG 1022
#define STOP_TAG 1023
#define NEGV (-10000.0f)
#define LOG2E 1.4426950408889634f
#define LN2 0.6931471805599453f
#define MARGIN2 40.0f   // lagged-shift slack (log2 units); r4/r6-proven exact

#define NGRP 8        // one replica group per XCD (blockIdx % 8 heuristic)
#define BPG 32        // blocks per group
#define NBLK (NGRP * BPG)
#define ROWS_PB 32    // rows per block; half-wave (32 lanes) per row
#define NTHR 1024     // 16 waves

#define TAG(u) ((unsigned)((u) >> 32))

// ---- agent-scope 64-bit payload+tag atomics ---------------------------------
// Within a replica group all traffic stays in one XCD's L2 (if the %8
// placement heuristic holds); agent scope keeps it correct either way.
static __device__ __forceinline__ unsigned long long ld_agent_u64(
    const unsigned long long* p) {
  return __hip_atomic_load(p, __ATOMIC_RELAXED, __HIP_MEMORY_SCOPE_AGENT);
}
static __device__ __forceinline__ void st_agent_u64(unsigned long long* p,
                                                    unsigned long long v) {
  __hip_atomic_store(p, v, __ATOMIC_RELAXED, __HIP_MEMORY_SCOPE_AGENT);
}

// ---- wave64 DPP reductions (VALU-only) -------------------------------------
template <int CTRL>
static __device__ __forceinline__ float dpp_mov(float x, float old) {
  return __int_as_float(__builtin_amdgcn_update_dpp(
      __float_as_int(old), __float_as_int(x), CTRL, 0xF, 0xF, false));
}
// sum over each 32-lane half -> lanes 31 and 63 hold their half's total
static __device__ __forceinline__ float half_red_sum(float x) {
  x += dpp_mov<0x111>(x, 0.0f);   // row_shr:1
  x += dpp_mov<0x112>(x, 0.0f);   // row_shr:2
  x += dpp_mov<0x114>(x, 0.0f);   // row_shr:4
  x += dpp_mov<0x118>(x, 0.0f);   // row_shr:8
  x += dpp_mov<0x142>(x, 0.0f);   // row_bcast:15
  return x;
}
// full 64-lane max -> lane 63
static __device__ __forceinline__ float wave_red_max63(float x) {
  const float NI = -3.0e38f;
  x = fmaxf(x, dpp_mov<0x111>(x, NI));
  x = fmaxf(x, dpp_mov<0x112>(x, NI));
  x = fmaxf(x, dpp_mov<0x114>(x, NI));
  x = fmaxf(x, dpp_mov<0x118>(x, NI));
  x = fmaxf(x, dpp_mov<0x142>(x, NI));
  x = fmaxf(x, dpp_mov<0x143>(x, NI));  // row_bcast:31
  return x;
}
// full 64-lane sum -> lane 63
static __device__ __forceinline__ float wave_red_sum63(float x) {
  x += dpp_mov<0x111>(x, 0.0f);
  x += dpp_mov<0x112>(x, 0.0f);
  x += dpp_mov<0x114>(x, 0.0f);
  x += dpp_mov<0x118>(x, 0.0f);
  x += dpp_mov<0x142>(x, 0.0f);
  x += dpp_mov<0x143>(x, 0.0f);
  return x;
}

// ---- workspace init: initial state (tag 1) in slot0, tag 0 in slot1,
//      for ALL 8 replica groups. Runs every call (replay-safe).
__global__ void init_ws_kernel(unsigned long long* fvbuf, int* bmax) {
  int i = blockIdx.x * blockDim.x + threadIdx.x;   // over 8*2*1024 entries
  if (i < NGRP * 2 * K_TAGS) {
    int e = i & (2 * K_TAGS - 1);
    int slot = e >> 10;
    int rr = e & (K_TAGS - 1);
    if (slot == 0) {
      float v = (rr == START_TAG) ? 0.0f : NEGV * LOG2E;
      fvbuf[i] = (1ull << 32) | (unsigned long long)__float_as_uint(v);
    } else {
      fvbuf[i] = 0ull;
    }
  }
  if (i == 0) *bmax = 0;  // float 0.0 bits; true max is positive
}

// ---- gates: one wave per step t; t==T_STEPS computes the terminal gate -----
__global__ __launch_bounds__(256) void gate_kernel(
    const float* __restrict__ reps, const float* __restrict__ wc,
    const float* __restrict__ wu, const int* __restrict__ spk,
    float* __restrict__ gate, float* __restrict__ g_term) {
  const int gw = (int)((blockIdx.x * blockDim.x + threadIdx.x) >> 6);
  const int lane = threadIdx.x & 63;
  if (gw > T_STEPS) return;
  const int tcur = (gw < T_STEPS) ? gw : (T_STEPS - 1);
  const int tprv = (gw < T_STEPS) ? (gw > 0 ? gw - 1 : 0) : (T_STEPS - 1);
  const float* cur = reps + (size_t)tcur * D_DIM;
  const float* prv = reps + (size_t)tprv * D_DIM;
  float sc = 0.f, su = 0.f;
#pragma unroll
  for (int c = 0; c < 4; ++c) {
    const int d = lane * 4 + c * 256;
    float4 rp = *(const float4*)(prv + d);
    float4 rc = *(const float4*)(cur + d);
    float4 w1 = *(const float4*)(wc + d);
    float4 w2 = *(const float4*)(wc + D_DIM + d);
    float4 w3 = *(const float4*)(wu + d);
    float4 w4 = *(const float4*)(wu + D_DIM + d);
    sc += rp.x * w1.x + rp.y * w1.y + rp.z * w1.z + rp.w * w1.w;
    sc += rc.x * w2.x + rc.y * w2.y + rc.z * w2.z + rc.w * w2.w;
    su += rp.x * w3.x + rp.y * w3.y + rp.z * w3.z + rp.w * w3.w;
    su += rc.x * w4.x + rc.y * w4.y + rc.z * w4.z + rc.w * w4.w;
  }
#pragma unroll
  for (int off = 32; off; off >>= 1) {
    sc += __shfl_xor(sc, off);
    su += __shfl_xor(su, off);
  }
  if (lane == 0) {
    if (gw < T_STEPS) {
      bool uc = (gw > 0) && (spk[gw] != 0);
      float x = uc ? sc : su;
      gate[gw] = 1.0f / (1.0f + __expf(-x));
    } else {
      *g_term = 1.0f / (1.0f + __expf(-su));
    }
  }
}

// ---- global max over elementwise max(ti, ta) (for the lagged LSE shift) ----
__global__ __launch_bounds__(256) void bmax_kernel(
    const float* __restrict__ ti, const float* __restrict__ ta, int* bmax) {
  size_t i = (size_t)blockIdx.x * blockDim.x + threadIdx.x;
  size_t n = (size_t)K_TAGS * K_TAGS;
  float m = 0.f;  // clamped at 0 so int-compare atomicMax is valid
  for (size_t j = i; j < n; j += (size_t)gridDim.x * blockDim.x)
    m = fmaxf(m, fmaxf(ti[j], ta[j]));
#pragma unroll
  for (int off = 32; off; off >>= 1) m = fmaxf(m, __shfl_xor(m, off));
  if ((threadIdx.x & 63) == 0) atomicMax(bmax, __float_as_int(m));
}

// ---- persistent CRF forward scan: 8 XCD-local replica groups ---------------
// Group g = blockIdx%8 (round-robin -> one XCD). 32 blocks/group, each block
// 1024 threads (16 waves), owns 32 rows (half-wave per row, 32 cells/thread).
// Every group redundantly computes the full recurrence; its fvbuf region is
// touched ONLY by its own blocks -> exchange lives in one XCD's L2.
__global__ __launch_bounds__(NTHR, 4) void crf_kernel(
    const float* __restrict__ feats, const float* __restrict__ ti,
    const float* __restrict__ ta, const float* __restrict__ gate,
    const float* __restrict__ g_term_p, const int* __restrict__ bmax_p,
    unsigned long long* fvbuf, float* __restrict__ out) {
  const int grp = blockIdx.x & (NGRP - 1);
  const int rank = blockIdx.x >> 3;
  const int tid = threadIdx.x;
  const int lane = tid & 63;
  const int w = tid >> 6;                 // wave id (0..15)
  const int j = lane & 31;                // team lane within half-wave
  const int h = lane >> 5;                // half id
  const int r = rank * ROWS_PB + 2 * w + h;  // this half-wave's row
  const bool leader = (j == 31);          // lanes 31 and 63

  unsigned long long* fvg = fvbuf + (size_t)grp * (2 * K_TAGS);

  __shared__ __align__(16) float fvs[2][K_TAGS];
  __shared__ __align__(16) float wredM[2][16];  // slot-buffered lagged blockmax
  __shared__ float wredS[16];

  // register-resident, log2-scaled matrix slice: 32 cells for row r
  float ta2[32], df2[32];
  {
    const float2* taP = reinterpret_cast<const float2*>(ta + (size_t)r * K_TAGS) + j;
    const float2* tiP = reinterpret_cast<const float2*>(ti + (size_t)r * K_TAGS) + j;
#pragma unroll
    for (int c = 0; c < 16; ++c) {
      float2 a = taP[32 * c];
      float2 i_ = tiP[32 * c];
      ta2[2 * c] = a.x * LOG2E;
      df2[2 * c] = (i_.x - a.x) * LOG2E;
      ta2[2 * c + 1] = a.y * LOG2E;
      df2[2 * c + 1] = (i_.y - a.y) * LOG2E;
    }
  }
  const float bmax2 = __int_as_float(*bmax_p) * LOG2E;

  // lagged-max buffers: max(fv_0) = 0 (START row), used at t=0
  if (tid < 32) wredM[tid >> 4][tid & 15] = 0.0f;
  // initial state was published by init_ws_kernel (tag 1 in slot 0)

  float featv = leader ? feats[r] : 0.0f;  // feats[0][r]

  for (int t = 0; t < T_STEPS; ++t) {
    const int slot = t & 1;
    const unsigned want = (unsigned)(t + 1);
    const float g = gate[t];  // uniform; overlaps the poll

    // 1) poll own tagged atom (one per thread; group-local line)
    unsigned long long* ep = &fvg[slot * K_TAGS + tid];
    unsigned long long u = ld_agent_u64(ep);
    while (TAG(u) < want) u = ld_agent_u64(ep);
    const float v = __uint_as_float((unsigned)u);

    // 2) stash -> one barrier
    fvs[slot][tid] = v;
    __syncthreads();

    // prefetch next step's emission; latency hides under compute
    float featv_next = 0.0f;
    if (leader && t + 1 < T_STEPS)
      featv_next = feats[(size_t)(t + 1) * K_TAGS + r];

    // 3) lagged shift: blockmax(fv_{t-1}) + bmax2 + margin (exact, r4-proven)
    const float4 mA = *reinterpret_cast<const float4*>(&wredM[slot ^ 1][0]);
    const float4 mB = *reinterpret_cast<const float4*>(&wredM[slot ^ 1][4]);
    const float4 mC = *reinterpret_cast<const float4*>(&wredM[slot ^ 1][8]);
    const float4 mD = *reinterpret_cast<const float4*>(&wredM[slot ^ 1][12]);
    float mm = fmaxf(fmaxf(fmaxf(mA.x, mA.y), fmaxf(mA.z, mA.w)),
                     fmaxf(fmaxf(mB.x, mB.y), fmaxf(mB.z, mB.w)));
    mm = fmaxf(mm, fmaxf(fmaxf(fmaxf(mC.x, mC.y), fmaxf(mC.z, mC.w)),
                         fmaxf(fmaxf(mD.x, mD.y), fmaxf(mD.z, mD.w))));
    const float sh = mm + bmax2 + MARGIN2;

    // 4) 32 cells: acc += 2^(ta2 + g*df2 + fv - sh); 2-way LDS access (free),
    //    both halves of a wave broadcast-read the same addresses
    float a0 = 0.f, a1 = 0.f;
    const float2* fp = reinterpret_cast<const float2*>(&fvs[slot][0]) + j;
#pragma unroll
    for (int c = 0; c < 16; ++c) {
      float2 f = fp[32 * c];
      a0 += exp2f(__builtin_fmaf(g, df2[2 * c], ta2[2 * c]) + (f.x - sh));
      a1 += exp2f(__builtin_fmaf(g, df2[2 * c + 1], ta2[2 * c + 1]) + (f.y - sh));
    }
    float acc = half_red_sum(a0 + a1);  // lanes 31/63 hold row sums

    // 5) leaders publish (tag t+2) into the other slot; rows 2w,2w+1 adjacent
    if (leader) {
      float fvnew = sh + __log2f(acc) + featv * LOG2E;  // -inf if acc==0: OK
      st_agent_u64(&fvg[(slot ^ 1) * K_TAGS + r],
                   ((unsigned long long)(unsigned)(t + 2) << 32) |
                       (unsigned long long)__float_as_uint(fvnew));
    }

    // 6) off critical path: wave max of polled fv_t -> wredM[slot] for t+1
    float lm = wave_red_max63(v);
    if (lane == 63) wredM[slot][w] = lm;

    featv = featv_next;
  }

  // ---- terminal LSE by group 0, rank 31 (blockIdx 248) -----------------------
  if (grp == 0 && rank == BPG - 1) {
    __syncthreads();  // all waves past their last wredM reads (race fix)
    const unsigned want = (unsigned)(T_STEPS + 1);
    unsigned long long* ep = &fvg[(T_STEPS & 1) * K_TAGS + tid];
    unsigned long long u = ld_agent_u64(ep);
    while (TAG(u) < want) u = ld_agent_u64(ep);
    const float gt = *g_term_p;
    const float tis = ti[(size_t)STOP_TAG * K_TAGS + tid];
    const float tas = ta[(size_t)STOP_TAG * K_TAGS + tid];
    const float term2 =
        __uint_as_float((unsigned)u) + (tas + gt * (tis - tas)) * LOG2E;

    float m = wave_red_max63(term2);
    if (lane == 63) wredM[0][w] = m;
    __syncthreads();
    float mm = wredM[0][0];
#pragma unroll
    for (int i = 1; i < 16; ++i) mm = fmaxf(mm, wredM[0][i]);
    float e = exp2f(term2 - mm);
    e = wave_red_sum63(e);
    if (lane == 63) wredS[w] = e;
    __syncthreads();
    if (tid == 0) {
      float s = 0.f;
#pragma unroll
      for (int i = 0; i < 16; ++i) s += wredS[i];
      out[0] = (mm + __log2f(s)) * LN2;
    }
  }
}

extern "C" void kernel_launch(void* const* d_in, const int* in_sizes, int n_in,
                              void* d_out, int out_size, void* d_ws, size_t ws_size,
                              hipStream_t stream) {
  (void)in_sizes; (void)n_in; (void)out_size; (void)ws_size;
  const float* feats = (const float*)d_in[0];
  const float* reps  = (const float*)d_in[1];
  const float* wc    = (const float*)d_in[2];
  const float* wu    = (const float*)d_in[3];
  const float* ti    = (const float*)d_in[4];
  const float* ta    = (const float*)d_in[5];
  const int*   spk   = (const int*)d_in[6];
  float* out = (float*)d_out;

  // ws layout: fvbuf[8 groups][2][1024] u64 (128 KiB) | gate[8192] f32
  //            | g_term f32 | bmax i32
  unsigned long long* fvbuf = (unsigned long long*)d_ws;
  float* gate  = (float*)((char*)d_ws +
                          (size_t)NGRP * 2 * K_TAGS * sizeof(unsigned long long));
  float* gterm = gate + T_STEPS;
  int*   bmax  = (int*)(gterm + 1);

  init_ws_kernel<<<dim3(64), dim3(256), 0, stream>>>(fvbuf, bmax);
  gate_kernel<<<dim3((T_STEPS + 1 + 3) / 4), dim3(256), 0, stream>>>(
      reps, wc, wu, spk, gate, gterm);
  bmax_kernel<<<dim3(512), dim3(256), 0, stream>>>(ti, ta, bmax);
  crf_kernel<<<dim3(NBLK), dim3(NTHR), 0, stream>>>(feats, ti, ta, gate, gterm,
                                                    bmax, fvbuf, out);
}